// Round 12
// baseline (321.126 us; speedup 1.0000x reference)
//
#include <hip/hip_runtime.h>

// CausalAffineAutoregFlow — MI355X bf16-MFMA implementation, round 12.
//
// R12: s/t role-split retry, engineered for 2 waves/SIMD (<=256 unified regs
// per wave). Block = 128 thr = 2 waves = one (s,t) pair owning 16 rows.
// Per wave: ONE MLP. A2 (28 frags = 112 regs) pinned AGPR; A1+A3 (44 regs)
// + working set in VGPR (~140). e read as per-step scalar loads (L1-hit;
// one 128B line per row serves all 32 steps) instead of 8 resident regs.
// Exchange of the two sigmoid scalars: single merged __shared__ array
// (masks @ [0..511], exchange @ [512..543] — rules out any separate-array
// layout aliasing), volatile, write -> barrier -> read -> barrier.
// All math paths (pack/pkrelu/slots/prepack) bit-identical to passing R7/R11.
//
// Slot conventions (R2/R7-identical):
//  - B/x/z/e per-lane slots j=0..7: logical dim = 8*(lane>>4)+j
//  - H-derived B chunk c slot (G,j): logical neuron 32c+(j>>2)*16+4G+(j&3)
//  - bias folds: b1 at dim-31 slot (x[31]==0 always since C[31][i]==0);
//    b2/b3 at padded neuron k==100 slot (chunk 3, G==1, j==0 := 1.0)

typedef __attribute__((ext_vector_type(8))) short short8;
typedef __attribute__((ext_vector_type(4))) float f32x4;
typedef __attribute__((ext_vector_type(4))) unsigned int uint4v;

#define WPK_U16 39936
#define MPK_OFF_BYTES 79872  // 39936*2, 16B aligned
#define NBLK 2048
#define REPS 4

__device__ __forceinline__ unsigned int bf16u(float v) {
  unsigned int b = __float_as_uint(v);
  b += 0x7FFFu + ((b >> 16) & 1u);   // RNE round to bf16
  return b >> 16;
}

// One-instruction packed f32->bf16x2 (lo = src0, hi = src1), RNE.
__device__ __forceinline__ unsigned int cvtpk(float lo, float hi) {
  unsigned int r;
  asm("v_cvt_pk_bf16_f32 %0, %1, %2" : "=v"(r) : "v"(lo), "v"(hi));
  return r;
}

// Packed relu on 2xbf16: i16 max with 0 (R7/R11-proven).
__device__ __forceinline__ unsigned int pkrelu(unsigned int x) {
  unsigned int r;
  asm("v_pk_max_i16 %0, %1, %2" : "=v"(r) : "v"(x), "v"(0u));
  return r;
}

// Pack 7 accumulator tiles -> 4 B-fragment chunks, relu in packed domain.
__device__ __forceinline__ void pack_h(const f32x4 (&h)[7], uint4v (&B)[4],
                                       bool g1) {
#pragma unroll
  for (int c = 0; c < 3; ++c) {
    B[c].x = pkrelu(cvtpk(h[2 * c][0], h[2 * c][1]));
    B[c].y = pkrelu(cvtpk(h[2 * c][2], h[2 * c][3]));
    B[c].z = pkrelu(cvtpk(h[2 * c + 1][0], h[2 * c + 1][1]));
    B[c].w = pkrelu(cvtpk(h[2 * c + 1][2], h[2 * c + 1][3]));
  }
  float v0 = g1 ? 1.0f : h[6][0];   // bias slot k==100 -> (G1,j0) := 1.0
  B[3].x = pkrelu(cvtpk(v0, h[6][1]));
  B[3].y = pkrelu(cvtpk(h[6][2], h[6][3]));
  B[3].z = 0u;
  B[3].w = 0u;
}

// Single-MLP evaluation (R7 math, one chain set). Pre-sigmoid scalar valid
// on ALL lanes (W3 row-replicated in prepack).
__device__ __forceinline__ float mlp_eval(const short8 (&a1)[7],
                                          const short8 (&a2)[7][4],
                                          const short8 (&a3)[4],
                                          short8 x, bool g1) {
  const f32x4 zz = {0.f, 0.f, 0.f, 0.f};
  f32x4 h1[7];
#pragma unroll
  for (int t = 0; t < 7; ++t)
    h1[t] = __builtin_amdgcn_mfma_f32_16x16x32_bf16(a1[t], x, zz, 0, 0, 0);
  uint4v B1[4];
  pack_h(h1, B1, g1);
  f32x4 h2[7];
#pragma unroll
  for (int t = 0; t < 7; ++t) h2[t] = zz;
#pragma unroll
  for (int c = 0; c < 4; ++c) {
    short8 B = __builtin_bit_cast(short8, B1[c]);
#pragma unroll
    for (int t = 0; t < 7; ++t)
      h2[t] = __builtin_amdgcn_mfma_f32_16x16x32_bf16(a2[t][c], B, h2[t], 0, 0, 0);
  }
  uint4v B2[4];
  pack_h(h2, B2, g1);
  f32x4 a0 = __builtin_amdgcn_mfma_f32_16x16x32_bf16(a3[0], __builtin_bit_cast(short8, B2[0]), zz, 0, 0, 0);
  f32x4 a1r = __builtin_amdgcn_mfma_f32_16x16x32_bf16(a3[1], __builtin_bit_cast(short8, B2[1]), zz, 0, 0, 0);
  f32x4 a2r = __builtin_amdgcn_mfma_f32_16x16x32_bf16(a3[2], __builtin_bit_cast(short8, B2[2]), zz, 0, 0, 0);
  f32x4 a3r = __builtin_amdgcn_mfma_f32_16x16x32_bf16(a3[3], __builtin_bit_cast(short8, B2[3]), zz, 0, 0, 0);
  return (a0[0] + a1r[0]) + (a2r[0] + a3r[0]);
}

// ---------------- prepack: fp32 weights -> packed bf16 A-fragments ----------
__global__ void prepack_kernel(const float *__restrict__ C,
                               const float *__restrict__ sW1, const float *__restrict__ sb1,
                               const float *__restrict__ sW2, const float *__restrict__ sb2,
                               const float *__restrict__ sW3, const float *__restrict__ sb3,
                               const float *__restrict__ tW1, const float *__restrict__ tb1,
                               const float *__restrict__ tW2, const float *__restrict__ tb2,
                               const float *__restrict__ tW3, const float *__restrict__ tb3,
                               unsigned short *__restrict__ wpk,
                               unsigned int *__restrict__ mpk) {
  int gid = blockIdx.x * 256 + threadIdx.x;
  if (gid < WPK_U16) {
    int which = gid / 19968;
    int a = gid % 19968;
    const float *W1 = which ? tW1 : sW1;
    const float *B1 = which ? tb1 : sb1;
    const float *W2 = which ? tW2 : sW2;
    const float *B2 = which ? tb2 : sb2;
    const float *W3 = which ? tW3 : sW3;
    const float *B3 = which ? tb3 : sb3;
    float v = 0.f;
    if (a < 3584) {                 // A1: [t][l][j]
      int t = a >> 9; int rem = a & 511; int l = rem >> 3; int j = rem & 7;
      int m = 16 * t + (l & 15);
      int d = 8 * (l >> 4) + j;
      if (m < 100) {
        if (d == 31) v = B1[m];     // bias via always-zero dim-31 slot
        else v = W1[d * 100 + m];
      }
    } else if (a < 17920) {         // A2: [t][c][l][j]
      int b = a - 3584; int tc = b >> 9; int t = tc >> 2; int c = tc & 3;
      int rem = b & 511; int l = rem >> 3; int j = rem & 7;
      int m = 16 * t + (l & 15);
      int k = 32 * c + (j >> 2) * 16 + 4 * (l >> 4) + (j & 3);
      if (m < 100) {
        if (k < 100) v = W2[k * 100 + m];
        else if (k == 100) v = B2[m];
      }
    } else {                        // A3: [c][l][j], REPLICATED across rows m
      int b = a - 17920; int c = b >> 9; int rem = b & 511;
      int l = rem >> 3; int j = rem & 7;
      int k = 32 * c + (j >> 2) * 16 + 4 * (l >> 4) + (j & 3);
      (void)l;
      if (k < 100) v = W3[k];
      else if (k == 100) v = B3[0];
    }
    wpk[gid] = (unsigned short)bf16u(v);
  } else if (gid < WPK_U16 + 512) { // AND-masks: [i][G][p]
    int idx = gid - WPK_U16;
    int i = idx >> 4;
    int G = (idx >> 2) & 3;
    int p = idx & 3;
    int d0 = 8 * G + 2 * p;
    unsigned int u = 0;
    if (C[d0 * 32 + i] != 0.f) u |= 0x0000FFFFu;
    if (C[(d0 + 1) * 32 + i] != 0.f) u |= 0xFFFF0000u;
    mpk[idx] = u;
  }
}

// ------------- main kernel: 2 waves = one (s,t) pair, 16 rows --------------
__global__ __launch_bounds__(128, 2) void flow_main(
    const float *__restrict__ e, const unsigned short *__restrict__ wpk,
    const unsigned int *__restrict__ mpk, float *__restrict__ out) {
  const int tid = threadIdx.x;
  const int role = tid >> 6;        // 0 = s-MLP wave, 1 = t-MLP wave
  const int lane = tid & 63;
  const int G = lane >> 4;
  const int bl = lane & 15;
  const bool g1 = (G == 1);
  const bool g3 = (G == 3);

  // Single merged shared block: masks [0..511], exchange floats [512..543].
  __shared__ __align__(16) unsigned int shm[544];
  volatile float *exf = (volatile float *)(shm + 512);
  ((uint4v *)shm)[tid] = ((const uint4v *)mpk)[tid & 127];  // 128 uint4 = msk
  if (tid < 32) exf[tid] = 0.f;

  // This wave's MLP weight fragments (one MLP only): 39 frags = 156 regs.
  const short8 *w = (const short8 *)wpk + (role ? 2496 : 0);
  short8 a1[7], a2[7][4], a3[4];
#pragma unroll
  for (int t = 0; t < 7; ++t) a1[t] = w[t * 64 + lane];
#pragma unroll
  for (int t = 0; t < 7; ++t)
#pragma unroll
    for (int c = 0; c < 4; ++c) a2[t][c] = w[448 + (t * 4 + c) * 64 + lane];
#pragma unroll
  for (int c = 0; c < 4; ++c) a3[c] = w[2240 + c * 64 + lane];
  // Pin A2 (112 regs) to AGPRs; A1/A3 + working set stay VGPR.
#pragma unroll
  for (int t = 0; t < 7; ++t)
#pragma unroll
    for (int c = 0; c < 4; ++c) asm volatile("" : "+a"(a2[t][c]));
  __syncthreads();

#pragma unroll 1
  for (int rep = 0; rep < REPS; ++rep) {
    const long base = ((long)blockIdx.x * REPS + rep) * 16;
    const long row = base + bl;
    const float *erow = e + row * 32;   // one 128B line: all 32 steps
    unsigned int z0 = 0, z1 = 0, z2 = 0, z3 = 0;  // z packed bf16, slots 0..7
    float ld = 0.f;
    uint4v m = *(const uint4v *)&shm[G * 4];      // mask for step 0

#pragma unroll 1
    for (int i8 = 0; i8 < 4; ++i8) {
      const bool tg = (G == i8);
#pragma unroll
      for (int u = 0; u < 8; ++u) {
        const int i = i8 * 8 + u;
        float es = erow[i];                        // L1-hit scalar load
        uint4v mn = *(const uint4v *)&shm[((i + 1) & 31) * 16 + G * 4];
        unsigned int x0 = z0 & m.x, x1 = z1 & m.y, x2 = z2 & m.z, x3 = z3 & m.w;
        if (g3) x3 = (x3 & 0x0000FFFFu) | 0x3F800000u;  // slot31 := 1.0
        uint4v xu; xu.x = x0; xu.y = x1; xu.z = x2; xu.w = x3;
        short8 x = __builtin_bit_cast(short8, xu);

        float pval = mlp_eval(a1, a2, a3, x, g1);
        float v = __fdividef(1.f, 1.f + __expf(-pval));  // sigmoid, all lanes

        exf[role * 16 + bl] = v;         // identical bits across G per bl
        __syncthreads();                 // write -> visible
        float other = exf[(role ^ 1) * 16 + bl];
        __syncthreads();                 // read done before next write
        float sv = role ? other : v;
        float tv = role ? v : other;
        ld += sv;

        float zn = __expf(sv) * es + tv;
        unsigned int r = cvtpk(zn, zn);
        const int p = (u >> 1) & 3;
        const bool hi = (u & 1) != 0;
        unsigned int mrg;
        if (p == 0) {
          mrg = hi ? ((z0 & 0x0000FFFFu) | (r & 0xFFFF0000u))
                   : ((z0 & 0xFFFF0000u) | (r & 0x0000FFFFu));
          z0 = tg ? mrg : z0;
        } else if (p == 1) {
          mrg = hi ? ((z1 & 0x0000FFFFu) | (r & 0xFFFF0000u))
                   : ((z1 & 0xFFFF0000u) | (r & 0x0000FFFFu));
          z1 = tg ? mrg : z1;
        } else if (p == 2) {
          mrg = hi ? ((z2 & 0x0000FFFFu) | (r & 0xFFFF0000u))
                   : ((z2 & 0xFFFF0000u) | (r & 0x0000FFFFu));
          z2 = tg ? mrg : z2;
        } else {
          mrg = hi ? ((z3 & 0x0000FFFFu) | (r & 0xFFFF0000u))
                   : ((z3 & 0xFFFF0000u) | (r & 0x0000FFFFu));
          z3 = tg ? mrg : z3;
        }
        m = mn;
      }
    }

    if (role == 0) {  // s-wave stores z and log_det
      float *zo = out + row * 32 + G * 8;
      f32x4 o0, o1;
      o0[0] = __uint_as_float(z0 << 16);
      o0[1] = __uint_as_float(z0 & 0xFFFF0000u);
      o0[2] = __uint_as_float(z1 << 16);
      o0[3] = __uint_as_float(z1 & 0xFFFF0000u);
      o1[0] = __uint_as_float(z2 << 16);
      o1[1] = __uint_as_float(z2 & 0xFFFF0000u);
      o1[2] = __uint_as_float(z3 << 16);
      o1[3] = __uint_as_float(z3 & 0xFFFF0000u);
      *(f32x4 *)zo = o0;
      *(f32x4 *)(zo + 4) = o1;
      if (lane < 16) out[(long)131072 * 32 + base + lane] = ld;
    }
  }
}

extern "C" void kernel_launch(void *const *d_in, const int *in_sizes, int n_in,
                              void *d_out, int out_size, void *d_ws, size_t ws_size,
                              hipStream_t stream) {
  const float *e  = (const float *)d_in[0];
  const float *C  = (const float *)d_in[1];
  const float *sW1 = (const float *)d_in[2];
  const float *sb1 = (const float *)d_in[3];
  const float *sW2 = (const float *)d_in[4];
  const float *sb2 = (const float *)d_in[5];
  const float *sW3 = (const float *)d_in[6];
  const float *sb3 = (const float *)d_in[7];
  const float *tW1 = (const float *)d_in[8];
  const float *tb1 = (const float *)d_in[9];
  const float *tW2 = (const float *)d_in[10];
  const float *tb2 = (const float *)d_in[11];
  const float *tW3 = (const float *)d_in[12];
  const float *tb3 = (const float *)d_in[13];

  unsigned short *wpk = (unsigned short *)d_ws;
  unsigned int *mpk = (unsigned int *)((char *)d_ws + MPK_OFF_BYTES);
  float *out = (float *)d_out;

  prepack_kernel<<<dim3(159), dim3(256), 0, stream>>>(
      C, sW1, sb1, sW2, sb2, sW3, sb3, tW1, tb1, tW2, tb2, tW3, tb3, wpk, mpk);
  flow_main<<<dim3(NBLK), dim3(128), 0, stream>>>(e, wpk, mpk, out);
}

// Round 13
// 301.941 us; speedup vs baseline: 1.0635x; 1.0635x over previous
//
#include <hip/hip_runtime.h>

// CausalAffineAutoregFlow — MI355X bf16-MFMA implementation, round 13.
//
// R13 = R11 weights/layout + 2-way cross-rep pipelining. One wave, 32 rows
// per step (two independent 16-row rep tiles A,B). Per step: four sequential
// single-MLP evals (sA, sB, tA, tB) — adjacent evals are independent chains,
// so each pack-wall (layer->cvtpk->layer) of one eval overlaps the MFMA
// stream of the next. This attacks the ~4000 cyc/step of dependency-wall
// stalls measured in R11 (5062 cyc/step vs ~1000 issue floor).
// A2+A3 of both MLPs pinned to AGPRs (256 exact); A1 (56) + ~170 working
// VGPRs. h2-init folded into chunk-0 MFMA. e via per-step scalar loads.
//
// Slot conventions (R2/R7/R11-identical):
//  - B/x/z/e per-lane slots j=0..7: logical dim = 8*(lane>>4)+j
//  - H-derived B chunk c slot (G,j): logical neuron 32c+(j>>2)*16+4G+(j&3)
//  - bias folds: b1 at dim-31 slot (x[31]==0 always since C[31][i]==0);
//    b2/b3 at padded neuron k==100 slot (chunk 3, G==1, j==0 := 1.0)

typedef __attribute__((ext_vector_type(8))) short short8;
typedef __attribute__((ext_vector_type(4))) float f32x4;
typedef __attribute__((ext_vector_type(4))) unsigned int uint4v;

#define WPK_U16 39936
#define MPK_OFF_BYTES 79872  // 39936*2, 16B aligned
#define NBLK 2048

__device__ __forceinline__ unsigned int bf16u(float v) {
  unsigned int b = __float_as_uint(v);
  b += 0x7FFFu + ((b >> 16) & 1u);   // RNE round to bf16
  return b >> 16;
}

// One-instruction packed f32->bf16x2 (lo = src0, hi = src1), RNE.
__device__ __forceinline__ unsigned int cvtpk(float lo, float hi) {
  unsigned int r;
  asm("v_cvt_pk_bf16_f32 %0, %1, %2" : "=v"(r) : "v"(lo), "v"(hi));
  return r;
}

// Packed relu on 2xbf16: i16 max with 0 (R7/R11-proven).
__device__ __forceinline__ unsigned int pkrelu(unsigned int x) {
  unsigned int r;
  asm("v_pk_max_i16 %0, %1, %2" : "=v"(r) : "v"(x), "v"(0u));
  return r;
}

// Pack 7 accumulator tiles -> 4 B-fragment chunks, relu in packed domain.
__device__ __forceinline__ void pack_h(const f32x4 (&h)[7], uint4v (&B)[4],
                                       bool g1) {
#pragma unroll
  for (int c = 0; c < 3; ++c) {
    B[c].x = pkrelu(cvtpk(h[2 * c][0], h[2 * c][1]));
    B[c].y = pkrelu(cvtpk(h[2 * c][2], h[2 * c][3]));
    B[c].z = pkrelu(cvtpk(h[2 * c + 1][0], h[2 * c + 1][1]));
    B[c].w = pkrelu(cvtpk(h[2 * c + 1][2], h[2 * c + 1][3]));
  }
  float v0 = g1 ? 1.0f : h[6][0];   // bias slot k==100 -> (G1,j0) := 1.0
  B[3].x = pkrelu(cvtpk(v0, h[6][1]));
  B[3].y = pkrelu(cvtpk(h[6][2], h[6][3]));
  B[3].z = 0u;
  B[3].w = 0u;
}

// Single-MLP evaluation (R12 math; h2-init folded into chunk-0 MFMA).
// Pre-sigmoid scalar valid on ALL lanes (W3 row-replicated in prepack).
__device__ __forceinline__ float mlp_eval(const short8 (&a1)[7],
                                          const short8 (&a2)[7][4],
                                          const short8 (&a3)[4],
                                          short8 x, bool g1) {
  const f32x4 zz = {0.f, 0.f, 0.f, 0.f};
  f32x4 h1[7];
#pragma unroll
  for (int t = 0; t < 7; ++t)
    h1[t] = __builtin_amdgcn_mfma_f32_16x16x32_bf16(a1[t], x, zz, 0, 0, 0);
  uint4v B1[4];
  pack_h(h1, B1, g1);
  f32x4 h2[7];
  {
    short8 B0 = __builtin_bit_cast(short8, B1[0]);
#pragma unroll
    for (int t = 0; t < 7; ++t)   // chunk 0 doubles as init (no zz movs)
      h2[t] = __builtin_amdgcn_mfma_f32_16x16x32_bf16(a2[t][0], B0, zz, 0, 0, 0);
  }
#pragma unroll
  for (int c = 1; c < 4; ++c) {
    short8 B = __builtin_bit_cast(short8, B1[c]);
#pragma unroll
    for (int t = 0; t < 7; ++t)
      h2[t] = __builtin_amdgcn_mfma_f32_16x16x32_bf16(a2[t][c], B, h2[t], 0, 0, 0);
  }
  uint4v B2[4];
  pack_h(h2, B2, g1);
  f32x4 a0 = __builtin_amdgcn_mfma_f32_16x16x32_bf16(a3[0], __builtin_bit_cast(short8, B2[0]), zz, 0, 0, 0);
  f32x4 a1r = __builtin_amdgcn_mfma_f32_16x16x32_bf16(a3[1], __builtin_bit_cast(short8, B2[1]), zz, 0, 0, 0);
  f32x4 a2r = __builtin_amdgcn_mfma_f32_16x16x32_bf16(a3[2], __builtin_bit_cast(short8, B2[2]), zz, 0, 0, 0);
  f32x4 a3r = __builtin_amdgcn_mfma_f32_16x16x32_bf16(a3[3], __builtin_bit_cast(short8, B2[3]), zz, 0, 0, 0);
  return (a0[0] + a1r[0]) + (a2r[0] + a3r[0]);
}

// ---------------- prepack: fp32 weights -> packed bf16 A-fragments ----------
__global__ void prepack_kernel(const float *__restrict__ C,
                               const float *__restrict__ sW1, const float *__restrict__ sb1,
                               const float *__restrict__ sW2, const float *__restrict__ sb2,
                               const float *__restrict__ sW3, const float *__restrict__ sb3,
                               const float *__restrict__ tW1, const float *__restrict__ tb1,
                               const float *__restrict__ tW2, const float *__restrict__ tb2,
                               const float *__restrict__ tW3, const float *__restrict__ tb3,
                               unsigned short *__restrict__ wpk,
                               unsigned int *__restrict__ mpk) {
  int gid = blockIdx.x * 256 + threadIdx.x;
  if (gid < WPK_U16) {
    int which = gid / 19968;
    int a = gid % 19968;
    const float *W1 = which ? tW1 : sW1;
    const float *B1 = which ? tb1 : sb1;
    const float *W2 = which ? tW2 : sW2;
    const float *B2 = which ? tb2 : sb2;
    const float *W3 = which ? tW3 : sW3;
    const float *B3 = which ? tb3 : sb3;
    float v = 0.f;
    if (a < 3584) {                 // A1: [t][l][j]
      int t = a >> 9; int rem = a & 511; int l = rem >> 3; int j = rem & 7;
      int m = 16 * t + (l & 15);
      int d = 8 * (l >> 4) + j;
      if (m < 100) {
        if (d == 31) v = B1[m];     // bias via always-zero dim-31 slot
        else v = W1[d * 100 + m];
      }
    } else if (a < 17920) {         // A2: [t][c][l][j]
      int b = a - 3584; int tc = b >> 9; int t = tc >> 2; int c = tc & 3;
      int rem = b & 511; int l = rem >> 3; int j = rem & 7;
      int m = 16 * t + (l & 15);
      int k = 32 * c + (j >> 2) * 16 + 4 * (l >> 4) + (j & 3);
      if (m < 100) {
        if (k < 100) v = W2[k * 100 + m];
        else if (k == 100) v = B2[m];
      }
    } else {                        // A3: [c][l][j], REPLICATED across rows m
      int b = a - 17920; int c = b >> 9; int rem = b & 511;
      int l = rem >> 3; int j = rem & 7;
      int k = 32 * c + (j >> 2) * 16 + 4 * (l >> 4) + (j & 3);
      (void)l;
      if (k < 100) v = W3[k];
      else if (k == 100) v = B3[0];
    }
    wpk[gid] = (unsigned short)bf16u(v);
  } else if (gid < WPK_U16 + 512) { // AND-masks: [i][G][p]
    int idx = gid - WPK_U16;
    int i = idx >> 4;
    int G = (idx >> 2) & 3;
    int p = idx & 3;
    int d0 = 8 * G + 2 * p;
    unsigned int u = 0;
    if (C[d0 * 32 + i] != 0.f) u |= 0x0000FFFFu;
    if (C[(d0 + 1) * 32 + i] != 0.f) u |= 0xFFFF0000u;
    mpk[idx] = u;
  }
}

// ------ main kernel: one wave, TWO independent 16-row tiles per step -------
__global__ __launch_bounds__(64, 1) void flow_main(
    const float *__restrict__ e, const unsigned short *__restrict__ wpk,
    const unsigned int *__restrict__ mpk, float *__restrict__ out) {
  const int lane = threadIdx.x;
  const int G = lane >> 4;
  const int bl = lane & 15;
  const bool g1 = (G == 1);
  const bool g3 = (G == 3);

  __shared__ __align__(16) unsigned int msk[512];
  {
    const uint4v *s = (const uint4v *)mpk;
    uint4v *d = (uint4v *)msk;
    d[lane] = s[lane];
    d[lane + 64] = s[lane + 64];
  }

  const short8 *w = (const short8 *)wpk;
  short8 a1s[7], a2s[7][4], a3s[4];
  short8 a1t[7], a2t[7][4], a3t[4];
#pragma unroll
  for (int t = 0; t < 7; ++t) a1s[t] = w[t * 64 + lane];
#pragma unroll
  for (int t = 0; t < 7; ++t)
#pragma unroll
    for (int c = 0; c < 4; ++c) a2s[t][c] = w[448 + (t * 4 + c) * 64 + lane];
#pragma unroll
  for (int c = 0; c < 4; ++c) a3s[c] = w[2240 + c * 64 + lane];
#pragma unroll
  for (int t = 0; t < 7; ++t) a1t[t] = w[2496 + t * 64 + lane];
#pragma unroll
  for (int t = 0; t < 7; ++t)
#pragma unroll
    for (int c = 0; c < 4; ++c)
      a2t[t][c] = w[2496 + 448 + (t * 4 + c) * 64 + lane];
#pragma unroll
  for (int c = 0; c < 4; ++c) a3t[c] = w[2496 + 2240 + c * 64 + lane];

  // Pin A2 (224) + A3 (32) to AGPRs — exactly the 256 AGPR file.
#pragma unroll
  for (int t = 0; t < 7; ++t)
#pragma unroll
    for (int c = 0; c < 4; ++c) {
      asm volatile("" : "+a"(a2s[t][c]));
      asm volatile("" : "+a"(a2t[t][c]));
    }
#pragma unroll
  for (int c = 0; c < 4; ++c) {
    asm volatile("" : "+a"(a3s[c]));
    asm volatile("" : "+a"(a3t[c]));
  }

#pragma unroll 1
  for (int rp = 0; rp < 2; ++rp) {
    const long baseA = ((long)blockIdx.x * 4 + rp * 2) * 16;
    const long baseB = baseA + 16;
    const float *erowA = e + (baseA + bl) * 32;   // one 128B line per row
    const float *erowB = e + (baseB + bl) * 32;
    unsigned int zA0 = 0, zA1 = 0, zA2 = 0, zA3 = 0;
    unsigned int zB0 = 0, zB1 = 0, zB2 = 0, zB3 = 0;
    float ldA = 0.f, ldB = 0.f;
    uint4v m = *(const uint4v *)&msk[G * 4];      // mask for step 0

#pragma unroll 1
    for (int i8 = 0; i8 < 4; ++i8) {
      const bool tg = (G == i8);
#pragma unroll
      for (int u = 0; u < 8; ++u) {
        const int i = i8 * 8 + u;
        float esA = erowA[i];                      // issue early; L1/L2 hit
        float esB = erowB[i];
        uint4v mn = *(const uint4v *)&msk[((i + 1) & 31) * 16 + G * 4];

        uint4v xa, xb;
        xa.x = zA0 & m.x; xa.y = zA1 & m.y; xa.z = zA2 & m.z; xa.w = zA3 & m.w;
        xb.x = zB0 & m.x; xb.y = zB1 & m.y; xb.z = zB2 & m.z; xb.w = zB3 & m.w;
        if (g3) {
          xa.w = (xa.w & 0x0000FFFFu) | 0x3F800000u;  // slot31 := 1.0
          xb.w = (xb.w & 0x0000FFFFu) | 0x3F800000u;
        }
        short8 xA = __builtin_bit_cast(short8, xa);
        short8 xB = __builtin_bit_cast(short8, xb);

        // 4 evals, pipelined pairwise: adjacent evals are independent, so
        // each pack-wall overlaps the neighbor's MFMA stream.
        float spA = mlp_eval(a1s, a2s, a3s, xA, g1);
        float spB = mlp_eval(a1s, a2s, a3s, xB, g1);
        float tpA = mlp_eval(a1t, a2t, a3t, xA, g1);
        float tpB = mlp_eval(a1t, a2t, a3t, xB, g1);

        float svA = __fdividef(1.f, 1.f + __expf(-spA));
        float tvA = __fdividef(1.f, 1.f + __expf(-tpA));
        float svB = __fdividef(1.f, 1.f + __expf(-spB));
        float tvB = __fdividef(1.f, 1.f + __expf(-tpB));
        ldA += svA;
        ldB += svB;

        float znA = __expf(svA) * esA + tvA;
        float znB = __expf(svB) * esB + tvB;
        unsigned int rA = cvtpk(znA, znA);
        unsigned int rB = cvtpk(znB, znB);
        const int p = (u >> 1) & 3;
        const bool hi = (u & 1) != 0;
        unsigned int mg;
        if (p == 0) {
          mg = hi ? ((zA0 & 0x0000FFFFu) | (rA & 0xFFFF0000u))
                  : ((zA0 & 0xFFFF0000u) | (rA & 0x0000FFFFu));
          zA0 = tg ? mg : zA0;
          mg = hi ? ((zB0 & 0x0000FFFFu) | (rB & 0xFFFF0000u))
                  : ((zB0 & 0xFFFF0000u) | (rB & 0x0000FFFFu));
          zB0 = tg ? mg : zB0;
        } else if (p == 1) {
          mg = hi ? ((zA1 & 0x0000FFFFu) | (rA & 0xFFFF0000u))
                  : ((zA1 & 0xFFFF0000u) | (rA & 0x0000FFFFu));
          zA1 = tg ? mg : zA1;
          mg = hi ? ((zB1 & 0x0000FFFFu) | (rB & 0xFFFF0000u))
                  : ((zB1 & 0xFFFF0000u) | (rB & 0x0000FFFFu));
          zB1 = tg ? mg : zB1;
        } else if (p == 2) {
          mg = hi ? ((zA2 & 0x0000FFFFu) | (rA & 0xFFFF0000u))
                  : ((zA2 & 0xFFFF0000u) | (rA & 0x0000FFFFu));
          zA2 = tg ? mg : zA2;
          mg = hi ? ((zB2 & 0x0000FFFFu) | (rB & 0xFFFF0000u))
                  : ((zB2 & 0xFFFF0000u) | (rB & 0x0000FFFFu));
          zB2 = tg ? mg : zB2;
        } else {
          mg = hi ? ((zA3 & 0x0000FFFFu) | (rA & 0xFFFF0000u))
                  : ((zA3 & 0xFFFF0000u) | (rA & 0x0000FFFFu));
          zA3 = tg ? mg : zA3;
          mg = hi ? ((zB3 & 0x0000FFFFu) | (rB & 0xFFFF0000u))
                  : ((zB3 & 0xFFFF0000u) | (rB & 0x0000FFFFu));
          zB3 = tg ? mg : zB3;
        }
        m = mn;
      }
    }

    float *zoA = out + (baseA + bl) * 32 + G * 8;
    float *zoB = out + (baseB + bl) * 32 + G * 8;
    f32x4 o;
    o[0] = __uint_as_float(zA0 << 16);
    o[1] = __uint_as_float(zA0 & 0xFFFF0000u);
    o[2] = __uint_as_float(zA1 << 16);
    o[3] = __uint_as_float(zA1 & 0xFFFF0000u);
    *(f32x4 *)zoA = o;
    o[0] = __uint_as_float(zA2 << 16);
    o[1] = __uint_as_float(zA2 & 0xFFFF0000u);
    o[2] = __uint_as_float(zA3 << 16);
    o[3] = __uint_as_float(zA3 & 0xFFFF0000u);
    *(f32x4 *)(zoA + 4) = o;
    o[0] = __uint_as_float(zB0 << 16);
    o[1] = __uint_as_float(zB0 & 0xFFFF0000u);
    o[2] = __uint_as_float(zB1 << 16);
    o[3] = __uint_as_float(zB1 & 0xFFFF0000u);
    *(f32x4 *)zoB = o;
    o[0] = __uint_as_float(zB2 << 16);
    o[1] = __uint_as_float(zB2 & 0xFFFF0000u);
    o[2] = __uint_as_float(zB3 << 16);
    o[3] = __uint_as_float(zB3 & 0xFFFF0000u);
    *(f32x4 *)(zoB + 4) = o;
    if (lane < 16) {
      out[(long)131072 * 32 + baseA + bl] = ldA;
      out[(long)131072 * 32 + baseB + bl] = ldB;
    }
  }
}

extern "C" void kernel_launch(void *const *d_in, const int *in_sizes, int n_in,
                              void *d_out, int out_size, void *d_ws, size_t ws_size,
                              hipStream_t stream) {
  const float *e  = (const float *)d_in[0];
  const float *C  = (const float *)d_in[1];
  const float *sW1 = (const float *)d_in[2];
  const float *sb1 = (const float *)d_in[3];
  const float *sW2 = (const float *)d_in[4];
  const float *sb2 = (const float *)d_in[5];
  const float *sW3 = (const float *)d_in[6];
  const float *sb3 = (const float *)d_in[7];
  const float *tW1 = (const float *)d_in[8];
  const float *tb1 = (const float *)d_in[9];
  const float *tW2 = (const float *)d_in[10];
  const float *tb2 = (const float *)d_in[11];
  const float *tW3 = (const float *)d_in[12];
  const float *tb3 = (const float *)d_in[13];

  unsigned short *wpk = (unsigned short *)d_ws;
  unsigned int *mpk = (unsigned int *)((char *)d_ws + MPK_OFF_BYTES);
  float *out = (float *)d_out;

  prepack_kernel<<<dim3(159), dim3(256), 0, stream>>>(
      C, sW1, sb1, sW2, sb2, sW3, sb3, tW1, tb1, tW2, tb2, tW3, tb3, wpk, mpk);
  flow_main<<<dim3(NBLK), dim3(64), 0, stream>>>(e, wpk, mpk, out);
}